// Round 8
// baseline (91.521 us; speedup 1.0000x reference)
//
#include <hip/hip_runtime.h>
#include <math.h>

typedef unsigned short u16;
typedef __attribute__((ext_vector_type(8))) short bf16x8;
typedef __attribute__((ext_vector_type(4))) float f32x4;

#define D_EMB 1152
#define NFR 4096
#define SQRT_D 33.94112549695428f

__device__ __forceinline__ u16 f2bf(float f) {
  unsigned u = __float_as_uint(f);
  u = (u + 0x7FFFu + ((u >> 16) & 1u)) >> 16;
  return (u16)u;
}
__device__ __forceinline__ float bf2f(u16 h) { return __uint_as_float(((unsigned)h) << 16); }

__device__ __forceinline__ void unpack8(uint4 g, float f[8]) {
  f[0] = bf2f((u16)(g.x & 0xffff)); f[1] = bf2f((u16)(g.x >> 16));
  f[2] = bf2f((u16)(g.y & 0xffff)); f[3] = bf2f((u16)(g.y >> 16));
  f[4] = bf2f((u16)(g.z & 0xffff)); f[5] = bf2f((u16)(g.z >> 16));
  f[6] = bf2f((u16)(g.w & 0xffff)); f[7] = bf2f((u16)(g.w >> 16));
}
__device__ __forceinline__ uint4 pack8(const float f[8]) {
  uint4 g;
  g.x = (unsigned)f2bf(f[0]) | ((unsigned)f2bf(f[1]) << 16);
  g.y = (unsigned)f2bf(f[2]) | ((unsigned)f2bf(f[3]) << 16);
  g.z = (unsigned)f2bf(f[4]) | ((unsigned)f2bf(f[5]) << 16);
  g.w = (unsigned)f2bf(f[6]) | ((unsigned)f2bf(f[7]) << 16);
  return g;
}

// ====== k_prep: [0,128) transpose+norms+colsum | [128,144) text norm | [144,656) local fusion ======
// Overlaid LDS (~19.2 KB) so occupancy is not LDS-capped.
__global__ __launch_bounds__(256) void k_prep(const float* __restrict__ fe,
                                              const float* __restrict__ text,
                                              u16* __restrict__ loc_n,
                                              u16* __restrict__ nf,
                                              u16* __restrict__ te_n,
                                              u16* __restrict__ nfT,
                                              float* __restrict__ invr,
                                              float* __restrict__ kpart,
                                              const float* __restrict__ tau_lp) {
  __shared__ __align__(16) char smem[19200];
  const int t = threadIdx.x;

  if (blockIdx.x < 128) {  // ---------- transpose + frame norms + colsum partials ----------
    float (*tile)[33] = (float(*)[33])smem;             // 4224 B
    float (*cred)[33] = (float(*)[33])(smem + 4224);    // 1056 B
    float* tinv = (float*)(smem + 5280);                // 128 B
    const int b2 = blockIdx.x;
    const int k0b = b2 * 32;
    {  // phase 1: row norms (8 threads per row, float4)
      int r = t >> 3, s = t & 7;
      const float4* row = (const float4*)(fe + (size_t)(k0b + r) * D_EMB);
      float ss = 0.f;
      for (int k = s; k < 288; k += 8) {
        float4 v = row[k];
        ss += v.x * v.x + v.y * v.y + v.z * v.z + v.w * v.w;
      }
      ss += __shfl_xor(ss, 1);
      ss += __shfl_xor(ss, 2);
      ss += __shfl_xor(ss, 4);
      if (s == 0) {
        float iv = 1.f / (sqrtf(ss) + 1e-6f);
        tinv[r] = iv;
        invr[k0b + r] = iv;
      }
    }
    __syncthreads();
    const int rr = t >> 3, cc = (t & 7) * 4;   // load mapping
    const int kl2 = (t & 15) * 2, dg = t >> 4; // nfT-write mapping
    const int col = t & 31, rgrp = t >> 5;     // colsum mapping
    float4 v = *(const float4*)(fe + (size_t)(k0b + rr) * D_EMB + cc);
    for (int d0 = 0; d0 < D_EMB; d0 += 32) {
      tile[rr][cc] = v.x; tile[rr][cc + 1] = v.y;
      tile[rr][cc + 2] = v.z; tile[rr][cc + 3] = v.w;
      __syncthreads();
      if (d0 + 32 < D_EMB)  // prefetch next tile (hides HBM latency under LDS phase)
        v = *(const float4*)(fe + (size_t)(k0b + rr) * D_EMB + d0 + 32 + cc);
      {  // colsum partials over rows
        float cs = tile[rgrp * 4 + 0][col] + tile[rgrp * 4 + 1][col] +
                   tile[rgrp * 4 + 2][col] + tile[rgrp * 4 + 3][col];
        cred[rgrp][col] = cs;
      }
      {  // transposed write: nfT[d][k], packed 2 k's per u32
        const float i0 = tinv[kl2], i1 = tinv[kl2 + 1];
#pragma unroll
        for (int s2 = 0; s2 < 2; ++s2) {
          int dl = dg + 16 * s2;
          unsigned pk = (unsigned)f2bf(tile[kl2][dl] * i0) |
                        ((unsigned)f2bf(tile[kl2 + 1][dl] * i1) << 16);
          *(unsigned*)(nfT + (size_t)(d0 + dl) * NFR + k0b + kl2) = pk;
        }
      }
      __syncthreads();
      if (t < 32) {
        float s2 = 0.f;
#pragma unroll
        for (int g = 0; g < 8; ++g) s2 += cred[g][t];
        kpart[b2 * D_EMB + d0 + t] = s2;
      }
    }
    return;
  }

  if (blockIdx.x < 144) {  // ---------- text row l2norm (eps=0) ----------
    float* wsum2 = (float*)smem;
    const int row = blockIdx.x - 128;
    const float* x = text + (size_t)row * D_EMB;
    float4 vv[2];
    float ss = 0.f;
#pragma unroll
    for (int i = 0; i < 2; ++i) {
      int idx = t + i * 256;
      if (idx < 288) {
        float4 v = ((const float4*)x)[idx];
        vv[i] = v;
        ss += v.x * v.x + v.y * v.y + v.z * v.z + v.w * v.w;
      }
    }
#pragma unroll
    for (int off = 32; off; off >>= 1) ss += __shfl_down(ss, off);
    if ((t & 63) == 0) wsum2[t >> 6] = ss;
    __syncthreads();
    float inv = 1.f / sqrtf(wsum2[0] + wsum2[1] + wsum2[2] + wsum2[3]);
#pragma unroll
    for (int i = 0; i < 2; ++i) {
      int idx = t + i * 256;
      if (idx < 288) {
        float4 v = vv[i];
        uint2 pk;
        pk.x = (unsigned)f2bf(v.x * inv) | ((unsigned)f2bf(v.y * inv) << 16);
        pk.y = (unsigned)f2bf(v.z * inv) | ((unsigned)f2bf(v.w * inv) << 16);
        *(uint2*)(te_n + (size_t)row * D_EMB + idx * 4) = pk;
      }
    }
    return;
  }

  // ---------- local fusion (one clip of 8 frames), bf16 clip in LDS ----------
  u16 (*clip)[1176] = (u16(*)[1176])smem;         // 18816 B (147 uint4-chunks/row; 144 valid)
  float* norms = (float*)(smem + 18816);
  float (*sc)[8] = (float(*)[8])(smem + 18848);
  float* nrm2 = (float*)(smem + 19104);
  const int c = blockIdx.x - 144;
  const float* src = fe + (size_t)c * 8 * D_EMB;
  for (int i = t; i < 2304; i += 256) {
    int r = i / 288, qd = i - r * 288;
    float4 v = ((const float4*)(src + r * D_EMB))[qd];
    uint2 pk;
    pk.x = (unsigned)f2bf(v.x) | ((unsigned)f2bf(v.y) << 16);
    pk.y = (unsigned)f2bf(v.z) | ((unsigned)f2bf(v.w) << 16);
    *(uint2*)&clip[r][qd * 4] = pk;
  }
  __syncthreads();
  {  // row norms
    int r = t >> 5, l32 = t & 31;
    float ss = 0.f;
    for (int ch = l32; ch < 144; ch += 32) {
      uint4 g = *(const uint4*)&clip[r][ch * 8];
      float f8[8];
      unpack8(g, f8);
#pragma unroll
      for (int e = 0; e < 8; ++e) ss += f8[e] * f8[e];
    }
#pragma unroll
    for (int off = 16; off; off >>= 1) ss += __shfl_xor(ss, off);
    if (l32 == 0) norms[r] = sqrtf(ss) + 1e-6f;
  }
  __syncthreads();
  {  // Gram: 36 symmetric pairs x 4 sub-lanes
    int p = t >> 2, sub = t & 3;
    if (p < 36) {
      int z = p, i = 0;
      while (z >= 8 - i) { z -= 8 - i; ++i; }
      int j = i + z;
      float s = 0.f;
      for (int ch = sub; ch < 144; ch += 4) {
        uint4 ga = *(const uint4*)&clip[i][ch * 8];
        uint4 gb = *(const uint4*)&clip[j][ch * 8];
        float fa[8], fb[8];
        unpack8(ga, fa);
        unpack8(gb, fb);
#pragma unroll
        for (int e = 0; e < 8; ++e) s += fa[e] * fb[e];
      }
      s += __shfl_xor(s, 1);
      s += __shfl_xor(s, 2);
      if (sub == 0) {
        float vv2 = s / (norms[i] * norms[j]);
        sc[i][j] = vv2;
        sc[j][i] = vv2;
      }
    }
  }
  __syncthreads();
  const float inv_tls = 1.f / (__expf(tau_lp[0]) * SQRT_D);
  if (t < 64) {
    int i = t >> 3, j = t & 7;
    float v = sc[i][j] * inv_tls;
    float mx = v;
#pragma unroll
    for (int off = 1; off < 8; off <<= 1) mx = fmaxf(mx, __shfl_xor(mx, off));
    float e = __expf(v - mx);
    float s = e;
#pragma unroll
    for (int off = 1; off < 8; off <<= 1) s += __shfl_xor(s, off);
    sc[i][j] = e / s;
  }
  __syncthreads();
  {  // fused output + nf
    int r = t >> 5, l32 = t & 31;
    float w[8];
#pragma unroll
    for (int j = 0; j < 8; ++j) w[j] = sc[r][j];
    const float invn_nf = 1.f / norms[r];
    if (l32 == 0) invr[c * 8 + r] = invn_nf;
    float av[5][8];
    float rs = 0.f;
#pragma unroll
    for (int kk = 0; kk < 5; ++kk) {
      int ch = l32 + kk * 32;
      if (ch < 144) {
        float acc8[8] = {0.f, 0.f, 0.f, 0.f, 0.f, 0.f, 0.f, 0.f};
#pragma unroll
        for (int j = 0; j < 8; ++j) {
          uint4 g = *(const uint4*)&clip[j][ch * 8];
          float f8[8];
          unpack8(g, f8);
          if (j == r) {
            float nf8[8];
#pragma unroll
            for (int e = 0; e < 8; ++e) nf8[e] = f8[e] * invn_nf;
            *(uint4*)(nf + (size_t)(c * 8 + r) * D_EMB + ch * 8) = pack8(nf8);
          }
#pragma unroll
          for (int e = 0; e < 8; ++e) acc8[e] += w[j] * f8[e];
        }
#pragma unroll
        for (int e = 0; e < 8; ++e) {
          av[kk][e] = acc8[e];
          rs += acc8[e] * acc8[e];
        }
      }
    }
#pragma unroll
    for (int off = 16; off; off >>= 1) rs += __shfl_xor(rs, off);
    if (l32 == 0) nrm2[r] = rs;
    __syncthreads();
    float invn = 1.f / sqrtf(nrm2[r]);
#pragma unroll
    for (int kk = 0; kk < 5; ++kk) {
      int ch = l32 + kk * 32;
      if (ch < 144) {
        float o8[8];
#pragma unroll
        for (int e = 0; e < 8; ++e) o8[e] = av[kk][e] * invn;
        *(uint4*)(loc_n + (size_t)(c * 8 + r) * D_EMB + ch * 8) = pack8(o8);
      }
    }
  }
}

// ==== scoreA: d0/d1 via MFMA; P1 = .9d0+.05d1, A0 = d0*rn, u = bf16(A0); blocks>=256: colsum ====
__global__ __launch_bounds__(256) void k_scoreA(const u16* __restrict__ te_n,
                                                const u16* __restrict__ nf,
                                                const u16* __restrict__ loc_n,
                                                const float* __restrict__ invr,
                                                const float* __restrict__ kpart,
                                                float* __restrict__ colsum,
                                                float* __restrict__ P1,
                                                float* __restrict__ A0,
                                                u16* __restrict__ ubf) {
  const int tid = threadIdx.x;
  if (blockIdx.x >= 256) {  // colsum reduce (9 blocks x 128 threads)
    if (tid < 128) {
      const int col = (blockIdx.x - 256) * 128 + tid;
      float s = 0.f;
      for (int kb = 0; kb < 128; ++kb) s += kpart[kb * D_EMB + col];
      colsum[col] = s;
    }
    return;
  }
  const int lane = tid & 63;
  const int wave = tid >> 6;
  const int f0 = blockIdx.x * 16;
  const int fr = lane & 15;
  const int k8 = (lane >> 4) * 8;
  const int kbase = wave * 288;
  f32x4 a0 = {}, a1 = {};
  const u16* teP = te_n + fr * D_EMB + kbase + k8;
  const u16* nfP = nf + (size_t)(f0 + fr) * D_EMB + kbase + k8;
  const u16* lcP = loc_n + (size_t)(f0 + fr) * D_EMB + kbase + k8;
#pragma unroll
  for (int kc = 0; kc < 9; ++kc) {
    bf16x8 aTe = *(const bf16x8*)(teP + kc * 32);
    bf16x8 bNf = *(const bf16x8*)(nfP + kc * 32);
    bf16x8 bLc = *(const bf16x8*)(lcP + kc * 32);
    a0 = __builtin_amdgcn_mfma_f32_16x16x32_bf16(aTe, bNf, a0, 0, 0, 0);
    a1 = __builtin_amdgcn_mfma_f32_16x16x32_bf16(aTe, bLc, a1, 0, 0, 0);
  }
  __shared__ float red[2][4][256];
#pragma unroll
  for (int r = 0; r < 4; ++r) {
    red[0][wave][lane * 4 + r] = a0[r];
    red[1][wave][lane * 4 + r] = a1[r];
  }
  __syncthreads();
  if (wave == 0) {
    const int f = f0 + fr;
    const float rn = 1.f / invr[f];
#pragma unroll
    for (int r = 0; r < 4; ++r) {
      int li = lane * 4 + r;
      float d0 = red[0][0][li] + red[0][1][li] + red[0][2][li] + red[0][3][li];
      float d1 = red[1][0][li] + red[1][1][li] + red[1][2][li] + red[1][3][li];
      int q = (lane >> 4) * 4 + r;
      P1[(size_t)q * NFR + f] = 0.9f * d0 + 0.05f * d1;
      float a = d0 * rn;
      A0[(size_t)q * NFR + f] = a;
      ubf[(size_t)q * NFR + f] = f2bf(a);
    }
  }
}

// ---- tg partials: tgpart[p][q][d] = (nfT . u^T) split-K 16; p = by*4+wave (64 partials) ----
__global__ __launch_bounds__(256) void k_tg(const u16* __restrict__ nfT,
                                            const u16* __restrict__ ubf,
                                            float* __restrict__ tgpart) {
  const int tid = threadIdx.x;
  const int lane = tid & 63;
  const int wave = tid >> 6;
  const int d0 = blockIdx.x * 128;
  const int kb = blockIdx.y * 256 + wave * 64;
  const int fr = lane & 15;
  const int k8 = (lane >> 4) * 8;
  f32x4 acc[8] = {};
#pragma unroll
  for (int ks = 0; ks < 2; ++ks) {
    int kk = kb + ks * 32;
    bf16x8 b = *(const bf16x8*)&ubf[(size_t)fr * NFR + kk + k8];
#pragma unroll
    for (int m = 0; m < 8; ++m) {
      bf16x8 a = *(const bf16x8*)&nfT[(size_t)(d0 + m * 16 + fr) * NFR + kk + k8];
      acc[m] = __builtin_amdgcn_mfma_f32_16x16x32_bf16(a, b, acc[m], 0, 0, 0);
    }
  }
  float* dst = tgpart + (size_t)(blockIdx.y * 4 + wave) * 16 * D_EMB;
  const int q = fr;
#pragma unroll
  for (int m = 0; m < 8; ++m) {
#pragma unroll
    for (int r = 0; r < 4; ++r) {
      int d = d0 + m * 16 + (lane >> 4) * 4 + r;
      dst[(size_t)q * D_EMB + d] = acc[m][r];
    }
  }
}

// ---- reduce 64 tg partials -> tg bf16 [16][1152]; block 72 computes tec[17] ----
__global__ __launch_bounds__(256) void k_tgred(const float* __restrict__ tgpart,
                                               const u16* __restrict__ te_n,
                                               const float* __restrict__ colsum,
                                               u16* __restrict__ tg,
                                               float* __restrict__ tec) {
  const int t = threadIdx.x;
  if (blockIdx.x < 72) {
    const int idx = blockIdx.x * 256 + t;
    float s = 0.f;
#pragma unroll
    for (int p = 0; p < 64; ++p) s += tgpart[(size_t)p * 18432 + idx];
    tg[idx] = f2bf(s);
  } else {
    if (t < 136) {
      const int v = t >> 3, s8 = t & 7;
      float s = 0.f;
      for (int i = s8; i < D_EMB; i += 8) {
        float a = (v < 16) ? bf2f(te_n[v * D_EMB + i]) : colsum[i];
        s += a * colsum[i];
      }
      s += __shfl_xor(s, 1);
      s += __shfl_xor(s, 2);
      s += __shfl_xor(s, 4);
      if (s8 == 0) tec[v] = s;
    }
  }
}

// ---- scoreB: dtg = tg.nf via MFMA; fuse with P1/A0/tec; max over q -> logits ----
__global__ __launch_bounds__(256) void k_scoreB(const u16* __restrict__ tg,
                                                const u16* __restrict__ nf,
                                                const float* __restrict__ P1,
                                                const float* __restrict__ A0,
                                                const float* __restrict__ tec,
                                                float* __restrict__ logits,
                                                const float* __restrict__ tau_gp,
                                                const float* __restrict__ lsp,
                                                const float* __restrict__ lbp) {
  const int tid = threadIdx.x;
  const int lane = tid & 63;
  const int wave = tid >> 6;
  const int f0 = blockIdx.x * 16;
  const int fr = lane & 15;
  const int k8 = (lane >> 4) * 8;
  const int kbase = wave * 288;
  f32x4 a2 = {};
  const u16* tgP = tg + fr * D_EMB + kbase + k8;
  const u16* nfP = nf + (size_t)(f0 + fr) * D_EMB + kbase + k8;
#pragma unroll
  for (int kc = 0; kc < 9; ++kc) {
    bf16x8 aTg = *(const bf16x8*)(tgP + kc * 32);
    bf16x8 bNf = *(const bf16x8*)(nfP + kc * 32);
    a2 = __builtin_amdgcn_mfma_f32_16x16x32_bf16(aTg, bNf, a2, 0, 0, 0);
  }
  __shared__ float red[4][256];
#pragma unroll
  for (int r = 0; r < 4; ++r) red[wave][lane * 4 + r] = a2[r];
  __syncthreads();
  if (wave == 0) {
    const float inv = 1.f / (__expf(tau_gp[0]) * SQRT_D);
    const float delta = inv * inv * (0.5f + inv * (1.f / 6.f) + inv * inv * (1.f / 24.f));
    const float rsq = rsqrtf(tec[16]);
    const float els = __expf(lsp[0]);
    const float bias = lbp[0];
    const int f = f0 + fr;
    float mx = -1e30f;
#pragma unroll
    for (int r = 0; r < 4; ++r) {
      int li = lane * 4 + r;
      float dtg = red[0][li] + red[1][li] + red[2][li] + red[3][li];
      int q = (lane >> 4) * 4 + r;
      float glob = (tec[q] + inv * dtg + delta * A0[(size_t)q * NFR + f]) * rsq;
      float fused = els * (P1[(size_t)q * NFR + f] + 0.05f * glob) + bias;
      mx = fmaxf(mx, fused);
    }
    mx = fmaxf(mx, __shfl_xor(mx, 16));
    mx = fmaxf(mx, __shfl_xor(mx, 32));
    if (lane < 16) logits[f0 + lane] = mx;
  }
}

// ---------------- softmax-pool per clip + loss ----------------
__global__ __launch_bounds__(512) void k_final(const float* __restrict__ logits,
                                               const float* __restrict__ labels,
                                               float* __restrict__ out) {
  const int t = threadIdx.x;
  float x[8];
  float m = -1e30f;
#pragma unroll
  for (int j = 0; j < 8; ++j) { x[j] = logits[t * 8 + j]; m = fmaxf(m, x[j]); }
  float se = 0, swx = 0;
#pragma unroll
  for (int j = 0; j < 8; ++j) { float e = __expf(x[j] - m); se += e; swx += e * x[j]; }
  float pooled = swx / se;
  out[1 + t] = pooled;
  float lab = labels[t * 8];
  __shared__ float red[8];
  float v = lab;
#pragma unroll
  for (int off = 32; off; off >>= 1) v += __shfl_down(v, off);
  if ((t & 63) == 0) red[t >> 6] = v;
  __syncthreads();
  float total = 0;
#pragma unroll
  for (int w = 0; w < 8; ++w) total += red[w];
  float mean = total * (1.f / 512.f);
  float wgt = pooled * (lab - mean);
  float lsg = (wgt >= 0.f) ? -log1pf(__expf(-wgt)) : (wgt - log1pf(__expf(wgt)));
  __syncthreads();
  float v2 = lsg;
#pragma unroll
  for (int off = 32; off; off >>= 1) v2 += __shfl_down(v2, off);
  if ((t & 63) == 0) red[t >> 6] = v2;
  __syncthreads();
  if (t == 0) {
    float tl = 0;
#pragma unroll
    for (int w = 0; w < 8; ++w) tl += red[w];
    out[0] = -tl;
  }
}

extern "C" void kernel_launch(void* const* d_in, const int* in_sizes, int n_in,
                              void* d_out, int out_size, void* d_ws, size_t ws_size,
                              hipStream_t stream) {
  const float* fe = (const float*)d_in[0];
  const float* text = (const float*)d_in[1];
  const float* labels = (const float*)d_in[2];
  const float* tau_lp = (const float*)d_in[3];
  const float* tau_gp = (const float*)d_in[4];
  const float* lsp = (const float*)d_in[5];
  const float* lbp = (const float*)d_in[6];
  float* out = (float*)d_out;
  char* ws = (char*)d_ws;

  // ws layout (bytes), 256-aligned, total ~34.4 MB:
  u16* nf = (u16*)(ws + 0);                 // 4096x1152 bf16
  u16* nfT = (u16*)(ws + 9437184);          // 1152x4096 bf16
  u16* loc_n = (u16*)(ws + 18874368);       // 4096x1152 bf16
  u16* te_n = (u16*)(ws + 28311552);        // 16x1152 bf16
  float* invr = (float*)(ws + 28348416);    // 4096 f32
  float* colsum = (float*)(ws + 28364800);  // 1152 f32
  float* kpart = (float*)(ws + 28369408);   // 128x1152 f32
  float* logits = (float*)(ws + 28959232);  // 4096 f32
  float* tec = (float*)(ws + 28975616);     // 17 f32
  float* P1 = (float*)(ws + 28975872);      // 16x4096 f32
  float* A0 = (float*)(ws + 29238016);      // 16x4096 f32
  u16* ubf = (u16*)(ws + 29500160);         // 16x4096 bf16
  float* tgpart = (float*)(ws + 29631232);  // 64x16x1152 f32
  u16* tg = (u16*)(ws + 34349824);          // 16x1152 bf16

  hipLaunchKernelGGL(k_prep, dim3(656), dim3(256), 0, stream, fe, text, loc_n, nf, te_n, nfT,
                     invr, kpart, tau_lp);
  hipLaunchKernelGGL(k_scoreA, dim3(265), dim3(256), 0, stream, te_n, nf, loc_n, invr, kpart,
                     colsum, P1, A0, ubf);
  hipLaunchKernelGGL(k_tg, dim3(9, 16), dim3(256), 0, stream, nfT, ubf, tgpart);
  hipLaunchKernelGGL(k_tgred, dim3(73), dim3(256), 0, stream, tgpart, te_n, colsum, tg, tec);
  hipLaunchKernelGGL(k_scoreB, dim3(256), dim3(256), 0, stream, tg, nf, P1, A0, tec, logits,
                     tau_gp, lsp, lbp);
  hipLaunchKernelGGL(k_final, dim3(1), dim3(512), 0, stream, logits, labels, out);
}

// Round 9
// 80.070 us; speedup vs baseline: 1.1430x; 1.1430x over previous
//
#include <hip/hip_runtime.h>
#include <math.h>

typedef unsigned short u16;
typedef __attribute__((ext_vector_type(8))) short bf16x8;
typedef __attribute__((ext_vector_type(4))) float f32x4;

#define D_EMB 1152
#define NFR 4096
#define SQRT_D 33.94112549695428f

__device__ __forceinline__ u16 f2bf(float f) {
  unsigned u = __float_as_uint(f);
  u = (u + 0x7FFFu + ((u >> 16) & 1u)) >> 16;
  return (u16)u;
}
__device__ __forceinline__ float bf2f(u16 h) { return __uint_as_float(((unsigned)h) << 16); }

// ======== k_gram: [0,512) one clip/block: Gram + softmax weights + invr; <128 also colsum; [512,528) text norm ========
__global__ __launch_bounds__(256) void k_gram(const float* __restrict__ fe,
                                              const float* __restrict__ text,
                                              float* __restrict__ wgt,
                                              float* __restrict__ invr,
                                              float* __restrict__ kpart,
                                              u16* __restrict__ te_n,
                                              const float* __restrict__ tau_lp) {
  __shared__ float part[4][36];
  __shared__ float scw[8][9];
  __shared__ float nrm[8];
  __shared__ float wsum2[4];
  const int t = threadIdx.x;

  if (blockIdx.x >= 512) {  // ---- text row l2norm (eps=0) ----
    const int row = blockIdx.x - 512;
    const float* x = text + (size_t)row * D_EMB;
    float4 vv[2];
    float ss = 0.f;
#pragma unroll
    for (int i = 0; i < 2; ++i) {
      int idx = t + i * 256;
      if (idx < 288) {
        float4 v = ((const float4*)x)[idx];
        vv[i] = v;
        ss += v.x * v.x + v.y * v.y + v.z * v.z + v.w * v.w;
      }
    }
#pragma unroll
    for (int off = 32; off; off >>= 1) ss += __shfl_down(ss, off);
    if ((t & 63) == 0) wsum2[t >> 6] = ss;
    __syncthreads();
    float inv = 1.f / sqrtf(wsum2[0] + wsum2[1] + wsum2[2] + wsum2[3]);
#pragma unroll
    for (int i = 0; i < 2; ++i) {
      int idx = t + i * 256;
      if (idx < 288) {
        float4 v = vv[i];
        uint2 pk;
        pk.x = (unsigned)f2bf(v.x * inv) | ((unsigned)f2bf(v.y * inv) << 16);
        pk.y = (unsigned)f2bf(v.z * inv) | ((unsigned)f2bf(v.w * inv) << 16);
        *(uint2*)(te_n + (size_t)row * D_EMB + idx * 4) = pk;
      }
    }
    return;
  }

  const int c = blockIdx.x;
  const int wv = t >> 6, lane = t & 63;
  const float* base = fe + (size_t)c * 8 * D_EMB;
  float s[36];
#pragma unroll
  for (int p = 0; p < 36; ++p) s[p] = 0.f;
  const int it0 = wv * 5;
  const int itn = (it0 + 5 < 18) ? it0 + 5 : 18;
  for (int it = it0; it < itn; ++it) {
    const int d = it * 64 + lane;
    float r8[8];
#pragma unroll
    for (int j = 0; j < 8; ++j) r8[j] = base[(size_t)j * D_EMB + d];
    {
      int p = 0;
#pragma unroll
      for (int i = 0; i < 8; ++i)
#pragma unroll
        for (int j = i; j < 8; ++j) {
          s[p] += r8[i] * r8[j];
          ++p;
        }
    }
  }
  {  // butterfly-reduce each pair-sum across the wave; lane p stores partial p
    int p = 0;
#pragma unroll
    for (int i = 0; i < 8; ++i)
#pragma unroll
      for (int j = i; j < 8; ++j) {
        float v = s[p];
#pragma unroll
        for (int off = 1; off < 64; off <<= 1) v += __shfl_xor(v, off);
        if (lane == p) part[wv][p] = v;
        ++p;
      }
  }
  __syncthreads();
  if (t < 36) {
    float tot = part[0][t] + part[1][t] + part[2][t] + part[3][t];
    int z = t, i = 0;
    while (z >= 8 - i) { z -= 8 - i; ++i; }
    int j = i + z;
    scw[i][j] = tot;
    scw[j][i] = tot;
  }
  __syncthreads();
  if (t < 8) {
    float n = sqrtf(scw[t][t]) + 1e-6f;
    nrm[t] = n;
    invr[c * 8 + t] = 1.f / n;
  }
  __syncthreads();
  const float inv_tls = 1.f / (__expf(tau_lp[0]) * SQRT_D);
  if (t < 64) {
    int i = t >> 3, j = t & 7;
    float v = scw[i][j] / (nrm[i] * nrm[j]) * inv_tls;
    float mx = v;
#pragma unroll
    for (int off = 1; off < 8; off <<= 1) mx = fmaxf(mx, __shfl_xor(mx, off));
    float e = __expf(v - mx);
    float ssum = e;
#pragma unroll
    for (int off = 1; off < 8; off <<= 1) ssum += __shfl_xor(ssum, off);
    wgt[c * 64 + t] = e / ssum;
  }
  if (blockIdx.x < 128) {  // colsum partials: 32 rows per block
    const float* rbase = fe + (size_t)blockIdx.x * 32 * D_EMB;
    for (int d = t; d < D_EMB; d += 256) {
      float ss2 = 0.f;
#pragma unroll 8
      for (int r2 = 0; r2 < 32; ++r2) ss2 += rbase[(size_t)r2 * D_EMB + d];
      kpart[blockIdx.x * D_EMB + d] = ss2;
    }
  }
}

// ======== k_apply: one frame/block (XCD-swizzled): fused = w.rows, writes nf + loc_n; >=4096 unused ========
#define APPLY_CHUNK(CH, AV)                                                              \
  {                                                                                      \
    float4 fu = {0.f, 0.f, 0.f, 0.f}, own = {0.f, 0.f, 0.f, 0.f};                        \
    _Pragma("unroll") for (int j = 0; j < 8; ++j) {                                      \
      float4 v = *(const float4*)(base + (size_t)j * D_EMB + (CH) * 4);                  \
      if (j == r) own = v;                                                               \
      fu.x += w_s[j] * v.x; fu.y += w_s[j] * v.y;                                        \
      fu.z += w_s[j] * v.z; fu.w += w_s[j] * v.w;                                        \
    }                                                                                    \
    uint2 pk;                                                                            \
    pk.x = (unsigned)f2bf(own.x * ivf) | ((unsigned)f2bf(own.y * ivf) << 16);            \
    pk.y = (unsigned)f2bf(own.z * ivf) | ((unsigned)f2bf(own.w * ivf) << 16);            \
    *(uint2*)(nf + (size_t)f * D_EMB + (CH) * 4) = pk;                                   \
    AV = fu;                                                                             \
    ss += fu.x * fu.x + fu.y * fu.y + fu.z * fu.z + fu.w * fu.w;                         \
  }

__global__ __launch_bounds__(256) void k_apply(const float* __restrict__ fe,
                                               const float* __restrict__ wgt,
                                               const float* __restrict__ invr,
                                               u16* __restrict__ nf,
                                               u16* __restrict__ loc_n) {
  __shared__ float w_s[8];
  __shared__ float red[4];
  const int t = threadIdx.x;
  const int c = blockIdx.x & 511;   // clip
  const int r = blockIdx.x >> 9;    // row-in-clip; all 8 frames of clip c share XCD c%8
  const int f = c * 8 + r;
  if (t < 8) w_s[t] = wgt[c * 64 + r * 8 + t];
  __syncthreads();
  const float ivf = invr[f];
  const float* base = fe + (size_t)c * 8 * D_EMB;
  float4 av0 = {0.f, 0.f, 0.f, 0.f}, av1 = {0.f, 0.f, 0.f, 0.f};
  float ss = 0.f;
  APPLY_CHUNK(t, av0)
  if (t < 32) APPLY_CHUNK(256 + t, av1)
#pragma unroll
  for (int off = 32; off; off >>= 1) ss += __shfl_down(ss, off);
  if ((t & 63) == 0) red[t >> 6] = ss;
  __syncthreads();
  const float invn = 1.f / sqrtf(red[0] + red[1] + red[2] + red[3]);
  {
    uint2 pk;
    pk.x = (unsigned)f2bf(av0.x * invn) | ((unsigned)f2bf(av0.y * invn) << 16);
    pk.y = (unsigned)f2bf(av0.z * invn) | ((unsigned)f2bf(av0.w * invn) << 16);
    *(uint2*)(loc_n + (size_t)f * D_EMB + t * 4) = pk;
  }
  if (t < 32) {
    uint2 pk;
    pk.x = (unsigned)f2bf(av1.x * invn) | ((unsigned)f2bf(av1.y * invn) << 16);
    pk.y = (unsigned)f2bf(av1.z * invn) | ((unsigned)f2bf(av1.w * invn) << 16);
    *(uint2*)(loc_n + (size_t)f * D_EMB + (256 + t) * 4) = pk;
  }
}

// ==== scoreA: d0/d1 via MFMA; P1, A0; then tg-partials (bf16) for its 16 frames; >=256: colsum ====
__global__ __launch_bounds__(256) void k_scoreA(const u16* __restrict__ te_n,
                                                const u16* __restrict__ nf,
                                                const u16* __restrict__ loc_n,
                                                const float* __restrict__ invr,
                                                const float* __restrict__ kpart,
                                                float* __restrict__ colsum,
                                                float* __restrict__ P1,
                                                float* __restrict__ A0,
                                                u16* __restrict__ tgpart) {
  const int tid = threadIdx.x;
  if (blockIdx.x >= 256) {  // colsum reduce (9 blocks x 128 threads over 128 partials)
    if (tid < 128) {
      const int col = (blockIdx.x - 256) * 128 + tid;
      float s = 0.f;
      for (int kb = 0; kb < 128; ++kb) s += kpart[kb * D_EMB + col];
      colsum[col] = s;
    }
    return;
  }
  const int lane = tid & 63;
  const int wave = tid >> 6;
  const int f0 = blockIdx.x * 16;
  const int fr = lane & 15;
  const int k8 = (lane >> 4) * 8;
  const int kbase = wave * 288;
  f32x4 a0 = {}, a1 = {};
  const u16* teP = te_n + fr * D_EMB + kbase + k8;
  const u16* nfP = nf + (size_t)(f0 + fr) * D_EMB + kbase + k8;
  const u16* lcP = loc_n + (size_t)(f0 + fr) * D_EMB + kbase + k8;
#pragma unroll
  for (int kc = 0; kc < 9; ++kc) {
    bf16x8 aTe = *(const bf16x8*)(teP + kc * 32);
    bf16x8 bNf = *(const bf16x8*)(nfP + kc * 32);
    bf16x8 bLc = *(const bf16x8*)(lcP + kc * 32);
    a0 = __builtin_amdgcn_mfma_f32_16x16x32_bf16(aTe, bNf, a0, 0, 0, 0);
    a1 = __builtin_amdgcn_mfma_f32_16x16x32_bf16(aTe, bLc, a1, 0, 0, 0);
  }
  __shared__ float red[2][4][256];
  __shared__ float u_lds[16][17];
#pragma unroll
  for (int r = 0; r < 4; ++r) {
    red[0][wave][lane * 4 + r] = a0[r];
    red[1][wave][lane * 4 + r] = a1[r];
  }
  __syncthreads();
  if (wave == 0) {
    const int f = f0 + fr;
    const float rn = 1.f / invr[f];
#pragma unroll
    for (int r = 0; r < 4; ++r) {
      int li = lane * 4 + r;
      float d0 = red[0][0][li] + red[0][1][li] + red[0][2][li] + red[0][3][li];
      float d1 = red[1][0][li] + red[1][1][li] + red[1][2][li] + red[1][3][li];
      int q = (lane >> 4) * 4 + r;
      P1[(size_t)q * NFR + f] = 0.9f * d0 + 0.05f * d1;
      float a = d0 * rn;
      A0[(size_t)q * NFR + f] = a;
      u_lds[fr][q] = a;
    }
  }
  __syncthreads();
  // tg partials: tgpart[b][q][d] = sum_{f in 16} nf[f][d] * u[f][q]  (bf16 out)
  const size_t pb = (size_t)blockIdx.x * 18432;
#pragma unroll
  for (int g = 0; g < 5; ++g) {
    const int d = g * 256 + tid;
    if (d < D_EMB) {
      float acc[16];
#pragma unroll
      for (int q = 0; q < 16; ++q) acc[q] = 0.f;
#pragma unroll
      for (int f = 0; f < 16; ++f) {
        float v = bf2f(nf[(size_t)(f0 + f) * D_EMB + d]);
#pragma unroll
        for (int q = 0; q < 16; ++q) acc[q] += v * u_lds[f][q];
      }
#pragma unroll
      for (int q = 0; q < 16; ++q) tgpart[pb + q * D_EMB + d] = f2bf(acc[q]);
    }
  }
}

// ---- reduce 256 bf16 tg partials -> tg bf16 [16][1152]; block 72 computes tec[17] ----
__global__ __launch_bounds__(256) void k_tgred(const u16* __restrict__ tgpart,
                                               const u16* __restrict__ te_n,
                                               const float* __restrict__ colsum,
                                               u16* __restrict__ tg,
                                               float* __restrict__ tec) {
  const int t = threadIdx.x;
  if (blockIdx.x < 72) {
    const int idx = blockIdx.x * 256 + t;
    float s = 0.f;
#pragma unroll 8
    for (int p = 0; p < 256; ++p) s += bf2f(tgpart[(size_t)p * 18432 + idx]);
    tg[idx] = f2bf(s);
  } else {
    if (t < 136) {
      const int v = t >> 3, s8 = t & 7;
      float s = 0.f;
      for (int i = s8; i < D_EMB; i += 8) {
        float a = (v < 16) ? bf2f(te_n[v * D_EMB + i]) : colsum[i];
        s += a * colsum[i];
      }
      s += __shfl_xor(s, 1);
      s += __shfl_xor(s, 2);
      s += __shfl_xor(s, 4);
      if (s8 == 0) tec[v] = s;
    }
  }
}

// ---- scoreB: dtg = tg.nf via MFMA; fuse with P1/A0/tec; max over q -> logits ----
__global__ __launch_bounds__(256) void k_scoreB(const u16* __restrict__ tg,
                                                const u16* __restrict__ nf,
                                                const float* __restrict__ P1,
                                                const float* __restrict__ A0,
                                                const float* __restrict__ tec,
                                                float* __restrict__ logits,
                                                const float* __restrict__ tau_gp,
                                                const float* __restrict__ lsp,
                                                const float* __restrict__ lbp) {
  const int tid = threadIdx.x;
  const int lane = tid & 63;
  const int wave = tid >> 6;
  const int f0 = blockIdx.x * 16;
  const int fr = lane & 15;
  const int k8 = (lane >> 4) * 8;
  const int kbase = wave * 288;
  f32x4 a2 = {};
  const u16* tgP = tg + fr * D_EMB + kbase + k8;
  const u16* nfP = nf + (size_t)(f0 + fr) * D_EMB + kbase + k8;
#pragma unroll
  for (int kc = 0; kc < 9; ++kc) {
    bf16x8 aTg = *(const bf16x8*)(tgP + kc * 32);
    bf16x8 bNf = *(const bf16x8*)(nfP + kc * 32);
    a2 = __builtin_amdgcn_mfma_f32_16x16x32_bf16(aTg, bNf, a2, 0, 0, 0);
  }
  __shared__ float red[4][256];
#pragma unroll
  for (int r = 0; r < 4; ++r) red[wave][lane * 4 + r] = a2[r];
  __syncthreads();
  if (wave == 0) {
    const float inv = 1.f / (__expf(tau_gp[0]) * SQRT_D);
    const float delta = inv * inv * (0.5f + inv * (1.f / 6.f) + inv * inv * (1.f / 24.f));
    const float rsq = rsqrtf(tec[16]);
    const float els = __expf(lsp[0]);
    const float bias = lbp[0];
    const int f = f0 + fr;
    float mx = -1e30f;
#pragma unroll
    for (int r = 0; r < 4; ++r) {
      int li = lane * 4 + r;
      float dtg = red[0][li] + red[1][li] + red[2][li] + red[3][li];
      int q = (lane >> 4) * 4 + r;
      float glob = (tec[q] + inv * dtg + delta * A0[(size_t)q * NFR + f]) * rsq;
      float fused = els * (P1[(size_t)q * NFR + f] + 0.05f * glob) + bias;
      mx = fmaxf(mx, fused);
    }
    mx = fmaxf(mx, __shfl_xor(mx, 16));
    mx = fmaxf(mx, __shfl_xor(mx, 32));
    if (lane < 16) logits[f0 + lane] = mx;
  }
}

// ---------------- softmax-pool per clip + loss ----------------
__global__ __launch_bounds__(512) void k_final(const float* __restrict__ logits,
                                               const float* __restrict__ labels,
                                               float* __restrict__ out) {
  const int t = threadIdx.x;
  float x[8];
  float m = -1e30f;
#pragma unroll
  for (int j = 0; j < 8; ++j) { x[j] = logits[t * 8 + j]; m = fmaxf(m, x[j]); }
  float se = 0, swx = 0;
#pragma unroll
  for (int j = 0; j < 8; ++j) { float e = __expf(x[j] - m); se += e; swx += e * x[j]; }
  float pooled = swx / se;
  out[1 + t] = pooled;
  float lab = labels[t * 8];
  __shared__ float red[8];
  float v = lab;
#pragma unroll
  for (int off = 32; off; off >>= 1) v += __shfl_down(v, off);
  if ((t & 63) == 0) red[t >> 6] = v;
  __syncthreads();
  float total = 0;
#pragma unroll
  for (int w = 0; w < 8; ++w) total += red[w];
  float mean = total * (1.f / 512.f);
  float wgt = pooled * (lab - mean);
  float lsg = (wgt >= 0.f) ? -log1pf(__expf(-wgt)) : (wgt - log1pf(__expf(wgt)));
  __syncthreads();
  float v2 = lsg;
#pragma unroll
  for (int off = 32; off; off >>= 1) v2 += __shfl_down(v2, off);
  if ((t & 63) == 0) red[t >> 6] = v2;
  __syncthreads();
  if (t == 0) {
    float tl = 0;
#pragma unroll
    for (int w = 0; w < 8; ++w) tl += red[w];
    out[0] = -tl;
  }
}

extern "C" void kernel_launch(void* const* d_in, const int* in_sizes, int n_in,
                              void* d_out, int out_size, void* d_ws, size_t ws_size,
                              hipStream_t stream) {
  const float* fe = (const float*)d_in[0];
  const float* text = (const float*)d_in[1];
  const float* labels = (const float*)d_in[2];
  const float* tau_lp = (const float*)d_in[3];
  const float* tau_gp = (const float*)d_in[4];
  const float* lsp = (const float*)d_in[5];
  const float* lbp = (const float*)d_in[6];
  float* out = (float*)d_out;
  char* ws = (char*)d_ws;

  // ws layout (bytes), 256-aligned, total ~29.7 MB:
  u16* nf = (u16*)(ws + 0);                 // 4096x1152 bf16
  u16* loc_n = (u16*)(ws + 9437184);        // 4096x1152 bf16
  u16* te_n = (u16*)(ws + 18874368);        // 16x1152 bf16
  float* invr = (float*)(ws + 18911232);    // 4096 f32
  float* wgt = (float*)(ws + 18927616);     // 512x8x8 f32
  float* colsum = (float*)(ws + 19058688);  // 1152 f32
  float* kpart = (float*)(ws + 19063296);   // 128x1152 f32
  float* logits = (float*)(ws + 19653120);  // 4096 f32
  float* tec = (float*)(ws + 19669504);     // 17 f32
  float* P1 = (float*)(ws + 19669760);      // 16x4096 f32
  float* A0 = (float*)(ws + 19931904);      // 16x4096 f32
  u16* tgpart = (u16*)(ws + 20194048);      // 256x16x1152 bf16
  u16* tg = (u16*)(ws + 29631232);          // 16x1152 bf16

  hipLaunchKernelGGL(k_gram, dim3(528), dim3(256), 0, stream, fe, text, wgt, invr, kpart, te_n,
                     tau_lp);
  hipLaunchKernelGGL(k_apply, dim3(4096), dim3(256), 0, stream, fe, wgt, invr, nf, loc_n);
  hipLaunchKernelGGL(k_scoreA, dim3(265), dim3(256), 0, stream, te_n, nf, loc_n, invr, kpart,
                     colsum, P1, A0, tgpart);
  hipLaunchKernelGGL(k_tgred, dim3(73), dim3(256), 0, stream, tgpart, te_n, colsum, tg, tec);
  hipLaunchKernelGGL(k_scoreB, dim3(256), dim3(256), 0, stream, tg, nf, P1, A0, tec, logits,
                     tau_gp, lsp, lbp);
  hipLaunchKernelGGL(k_final, dim3(1), dim3(512), 0, stream, logits, labels, out);
}